// Round 5
// baseline (151.639 us; speedup 1.0000x reference)
//
#include <hip/hip_runtime.h>
#include <math.h>

#define B 8
#define T 128
#define NKEY 127   // t-1
#define NPAD 128   // padded key count (score row 127 forced to prob 0)
#define KDIM 64    // Q_DIM == KV_DIM
#define NH 4       // heads
#define CH 256     // NH*KDIM output channels

typedef short short8 __attribute__((ext_vector_type(8)));   // 8 bf16 (4 VGPRs)
typedef float floatx4 __attribute__((ext_vector_type(4)));  // MFMA C/D

// tanh(x) = 1 - 2/(e^{2x}+1). Saturates correctly at +/-inf, no clamp needed.
__device__ __forceinline__ float fast_tanh(float x) {
    float e = __expf(2.f * x);
    float r = __builtin_amdgcn_rcpf(e + 1.f);
    return fmaf(-2.f, r, 1.f);
}

// Truncation split: x = hi + lo, both bf16 (3-pass MFMA reconstructs ~fp32).
__device__ __forceinline__ void split8(const float4& a, const float4& b,
                                       short8& hi, short8& lo) {
    float x[8] = {a.x, a.y, a.z, a.w, b.x, b.y, b.z, b.w};
    #pragma unroll
    for (int i = 0; i < 8; ++i) {
        unsigned u = __float_as_uint(x[i]);
        hi[i] = (short)(u >> 16);                          // trunc to bf16
        float l = x[i] - __uint_as_float(u & 0xFFFF0000u); // exact residual
        lo[i] = (short)(__float_as_uint(l) >> 16);         // trunc residual
    }
}

// One workgroup per (b,t): 4 waves; wave h == head h.
// R5: Phase B from a REGISTER-resident kv tile (wave h holds rows 32h..32h+31,
// col = lane) instead of re-reading kv from global (R4's FETCH doubled: the
// re-read missed L2 and ran at ~1 TB/s => ~30 us of the 48).
// All-head partials per wave + LDS cross-wave reduce; value path exact fp32.
__global__ __launch_bounds__(256, 4)
void attn_kernel(const float* __restrict__ q_x,   // (B,T,64)
                 const float* __restrict__ kv_x,  // (B,T,127,64)
                 const float* __restrict__ Wk,    // (256,64)
                 const float* __restrict__ Wq,    // (256,64)
                 const float* __restrict__ Wv,    // (256,64)
                 const float* __restrict__ bias,  // (64,)
                 const float* __restrict__ Ws,    // (1,64)
                 const float* __restrict__ bs,    // (1,) -- cancels in softmax
                 float* __restrict__ out)         // (B,T,256)
{
    __shared__ __align__(16) short bh_lds[16][64][8];    // 16 KB: B-frag hi [chunk][lane][8]
    __shared__ __align__(16) short bl_lds[16][64][8];    // 16 KB: B-frag lo
    __shared__ float qb_lds[CH];                         // 1 KB: query+bias per channel
    __shared__ float p_lds[NH][NPAD];                    // 2 KB: scores then probs
    __shared__ float part_lds[NH][NH][KDIM];             // 4 KB: [head][wave][k] partials
    __shared__ float wkv_lds[NH][KDIM];                  // 1 KB

    const int bt   = blockIdx.x;
    const int tid  = threadIdx.x;
    const int h    = tid >> 6;    // wave index == head index
    const int lane = tid & 63;
    const int col  = lane & 15;   // MFMA n/m lane index
    const int quad = lane >> 4;   // MFMA k-group / row-group

    const float* __restrict__ kvg = kv_x + (size_t)bt * NKEY * KDIM;

    // ---- register-resident kv slice: rows 32h..32h+31, column k = lane ----
    // (coalesced dword loads; same lines as the conversion loads -> cache-hot)
    float kvreg[32];
    #pragma unroll
    for (int i = 0; i < 32; ++i) {
        const int n = 32 * h + i;
        kvreg[i] = (n < NKEY) ? kvg[(size_t)n * KDIM + lane] : 0.f;
    }

    // ---- convert kv (global) -> fragment-ordered bf16 hi/lo LDS ----
    // chunk = nt*2+ks; write addr = chunk*1024 + lane*16: lane-linear, conflict-free.
    // Fragment content: kv[nt*16 + (lane&15)][ks*32 + (lane>>4)*8 + j]
    #pragma unroll
    for (int w = 0; w < 4; ++w) {
        const int chunk = w * 4 + h;          // each wave does 4 chunks
        const int nt = chunk >> 1, ks = chunk & 1;
        const int n  = nt * 16 + (lane & 15);
        const int k0 = ks * 32 + (lane >> 4) * 8;
        float4 a = make_float4(0.f, 0.f, 0.f, 0.f);
        float4 b = make_float4(0.f, 0.f, 0.f, 0.f);
        if (n < NKEY) {
            const float* p = kvg + (size_t)n * KDIM + k0;
            a = *(const float4*)p;
            b = *(const float4*)(p + 4);
        }
        short8 hi, lo;
        split8(a, b, hi, lo);
        *(short8*)&bh_lds[chunk][lane][0] = hi;
        *(short8*)&bl_lds[chunk][lane][0] = lo;
    }

    // ---- query_j + bias -> qb_lds[channel] ----
    {
        const float4* Wq4 = (const float4*)(Wq + (size_t)tid * KDIM);
        const float4* q4g = (const float4*)(q_x + (size_t)bt * KDIM);
        float4 qa = {0.f, 0.f, 0.f, 0.f};
        #pragma unroll
        for (int i = 0; i < 16; ++i) {
            float4 w = Wq4[i];
            float4 q4 = q4g[i];
            qa.x = fmaf(q4.x, w.x, qa.x);
            qa.y = fmaf(q4.y, w.y, qa.y);
            qa.z = fmaf(q4.z, w.z, qa.z);
            qa.w = fmaf(q4.w, w.w, qa.w);
        }
        qb_lds[tid] = (qa.x + qa.y) + (qa.z + qa.w) + bias[tid & 63];
    }

    // ---- A-fragments (Wk rows of this head) from global, split hi/lo ----
    short8 ahi[4][2], alo[4][2];
    #pragma unroll
    for (int jt = 0; jt < 4; ++jt)
        #pragma unroll
        for (int ks = 0; ks < 2; ++ks) {
            const float* wrow = Wk + (size_t)(h * 64 + jt * 16 + col) * KDIM
                                   + ks * 32 + quad * 8;
            float4 a = *(const float4*)wrow;
            float4 b = *(const float4*)(wrow + 4);
            split8(a, b, ahi[jt][ks], alo[jt][ks]);
        }

    __syncthreads();   // barrier 1: frags + qb ready

    // ---- per-lane qb / ws for epilogue: j = jt*16 + quad*4 + r ----
    float qbv[4][4], wsv[4][4];
    #pragma unroll
    for (int jt = 0; jt < 4; ++jt)
        #pragma unroll
        for (int r = 0; r < 4; ++r) {
            int j = jt * 16 + quad * 4 + r;
            qbv[jt][r] = qb_lds[h * 64 + j];
            wsv[jt][r] = Ws[j];
        }

    // ---- scores: 8 n-tiles of 16 keys; 3-pass split-bf16 MFMA ----
    for (int nt = 0; nt < 8; ++nt) {
        short8 bhi0 = *(const short8*)&bh_lds[nt * 2 + 0][lane][0];
        short8 blo0 = *(const short8*)&bl_lds[nt * 2 + 0][lane][0];
        short8 bhi1 = *(const short8*)&bh_lds[nt * 2 + 1][lane][0];
        short8 blo1 = *(const short8*)&bl_lds[nt * 2 + 1][lane][0];

        floatx4 acc[4];
        #pragma unroll
        for (int jt = 0; jt < 4; ++jt) {
            floatx4 c = {0.f, 0.f, 0.f, 0.f};
            c = __builtin_amdgcn_mfma_f32_16x16x32_bf16(ahi[jt][0], bhi0, c, 0, 0, 0);
            c = __builtin_amdgcn_mfma_f32_16x16x32_bf16(ahi[jt][1], bhi1, c, 0, 0, 0);
            c = __builtin_amdgcn_mfma_f32_16x16x32_bf16(ahi[jt][0], blo0, c, 0, 0, 0);
            c = __builtin_amdgcn_mfma_f32_16x16x32_bf16(ahi[jt][1], blo1, c, 0, 0, 0);
            c = __builtin_amdgcn_mfma_f32_16x16x32_bf16(alo[jt][0], bhi0, c, 0, 0, 0);
            c = __builtin_amdgcn_mfma_f32_16x16x32_bf16(alo[jt][1], bhi1, c, 0, 0, 0);
            acc[jt] = c;
        }

        // epilogue: score[n] = sum_j tanh(key + qb[j]) * ws[j]
        // D layout: col = lane&15 = n in tile, row = quad*4 + r = j in jt
        float partial = 0.f;
        #pragma unroll
        for (int jt = 0; jt < 4; ++jt)
            #pragma unroll
            for (int r = 0; r < 4; ++r)
                partial = fmaf(fast_tanh(acc[jt][r] + qbv[jt][r]), wsv[jt][r], partial);
        partial += __shfl_xor(partial, 16, 64);   // reduce across quads (same col)
        partial += __shfl_xor(partial, 32, 64);
        if (lane < 16) p_lds[h][nt * 16 + lane] = partial;
    }
    // no barrier yet: wave h is sole writer+reader of p_lds[h][*] until probs

    // ---- softmax over the 127 real keys (2 scores per lane) ----
    float invl;
    {
        float s_a = p_lds[h][lane];
        float s_b = p_lds[h][64 + lane];
        if (lane == 63) s_b = -1e30f;          // mask pad row 127
        float mx = fmaxf(s_a, s_b);
        #pragma unroll
        for (int off = 32; off > 0; off >>= 1)
            mx = fmaxf(mx, __shfl_xor(mx, off, 64));
        float pa = __expf(s_a - mx);
        float pb = __expf(s_b - mx);           // lane 63 -> 0
        float ls = pa + pb;
        #pragma unroll
        for (int off = 32; off > 0; off >>= 1)
            ls += __shfl_xor(ls, off, 64);
        invl = 1.f / ls;                       // per-head, stays in wave h's regs
        p_lds[h][lane]      = pa;              // unnormalized probs
        p_lds[h][64 + lane] = pb;              // p_lds[h][127] = 0 masks pad
    }

    __syncthreads();   // barrier 2: all heads' probs visible to all waves

    // ---- Phase B: per-wave partials for ALL heads from kv registers ----
    // part[h2] = sum_{i<32} p[h2][32h+i] * kv[32h+i][lane]
    {
        float part[NH] = {0.f, 0.f, 0.f, 0.f};
        #pragma unroll
        for (int i4 = 0; i4 < 32; i4 += 4) {
            #pragma unroll
            for (int h2 = 0; h2 < NH; ++h2) {
                float4 p4 = *(const float4*)&p_lds[h2][32 * h + i4];  // uniform broadcast
                part[h2] = fmaf(p4.x, kvreg[i4 + 0],
                           fmaf(p4.y, kvreg[i4 + 1],
                           fmaf(p4.z, kvreg[i4 + 2],
                           fmaf(p4.w, kvreg[i4 + 3], part[h2]))));
            }
        }
        #pragma unroll
        for (int h2 = 0; h2 < NH; ++h2)
            part_lds[h2][h][lane] = part[h2];   // lane-linear writes
    }

    __syncthreads();   // barrier 3: partials ready

    // ---- cross-wave reduce + normalize (wave h owns head h; invl in regs) ----
    wkv_lds[h][lane] = (part_lds[h][0][lane] + part_lds[h][1][lane]
                      + part_lds[h][2][lane] + part_lds[h][3][lane]) * invl;
    // no barrier: wkv_lds[h] written and read only by wave h

    // ---- Phase C: out[j] = wkv[h,:] . Wv[j,:] ----
    {
        const float4* Wv4 = (const float4*)(Wv + (size_t)tid * KDIM);
        const float4* wv_row = (const float4*)wkv_lds[h];
        float4 oa = {0.f, 0.f, 0.f, 0.f};
        #pragma unroll
        for (int i = 0; i < 16; ++i) {
            float4 w = Wv4[i];
            float4 c = wv_row[i];                        // broadcast
            oa.x = fmaf(c.x, w.x, oa.x);
            oa.y = fmaf(c.y, w.y, oa.y);
            oa.z = fmaf(c.z, w.z, oa.z);
            oa.w = fmaf(c.w, w.w, oa.w);
        }
        out[(size_t)bt * CH + tid] = (oa.x + oa.y) + (oa.z + oa.w);
    }
}

extern "C" void kernel_launch(void* const* d_in, const int* in_sizes, int n_in,
                              void* d_out, int out_size, void* d_ws, size_t ws_size,
                              hipStream_t stream) {
    const float* q_x  = (const float*)d_in[0];
    const float* kv_x = (const float*)d_in[1];
    const float* Wk   = (const float*)d_in[2];
    const float* Wq   = (const float*)d_in[3];
    const float* Wv   = (const float*)d_in[4];
    const float* bias = (const float*)d_in[5];
    const float* Ws   = (const float*)d_in[6];
    const float* bs   = (const float*)d_in[7];
    float* out = (float*)d_out;

    attn_kernel<<<dim3(B * T), dim3(256), 0, stream>>>(
        q_x, kv_x, Wk, Wq, Wv, bias, Ws, bs, out);
}

// Round 6
// 151.108 us; speedup vs baseline: 1.0035x; 1.0035x over previous
//
#include <hip/hip_runtime.h>
#include <math.h>

#define B 8
#define T 128
#define NKEY 127   // t-1
#define NPAD 128   // padded key count (row 127 zeroed; prob forced to 0)
#define KDIM 64    // Q_DIM == KV_DIM
#define NH 4       // heads
#define CH 256     // NH*KDIM output channels
#define PITCH 68   // floats per kv row in LDS: 16B-aligned, bank-balanced

typedef short short8 __attribute__((ext_vector_type(8)));   // 8 bf16 (4 VGPRs)
typedef float floatx4 __attribute__((ext_vector_type(4)));  // MFMA C/D

// tanh(x) = 1 - 2/(e^{2x}+1). Saturates correctly at +/-inf, no clamp needed.
__device__ __forceinline__ float fast_tanh(float x) {
    float e = __expf(2.f * x);
    float r = __builtin_amdgcn_rcpf(e + 1.f);
    return fmaf(-2.f, r, 1.f);
}

// Truncation split: x = hi + lo, both bf16 (3-pass MFMA reconstructs ~fp32).
__device__ __forceinline__ void split8(const float4& a, const float4& b,
                                       short8& hi, short8& lo) {
    float x[8] = {a.x, a.y, a.z, a.w, b.x, b.y, b.z, b.w};
    #pragma unroll
    for (int i = 0; i < 8; ++i) {
        unsigned u = __float_as_uint(x[i]);
        hi[i] = (short)(u >> 16);                          // trunc to bf16
        float l = x[i] - __uint_as_float(u & 0xFFFF0000u); // exact residual
        lo[i] = (short)(__float_as_uint(l) >> 16);         // trunc residual
    }
}

// One workgroup per (b,t): 4 waves; wave h == head h.
// R6: single padded fp32 kv copy in LDS serves BOTH the MFMA B-fragments
// (split to bf16 hi/lo on the fly, in registers) AND the exact-fp32 Phase B
// weighted sum. Kills R4's global re-read (FETCH doubling) and R5's register
// spill (WRITE_SIZE 46 MB of scratch). A-side processed in 2 passes of 2
// j-tiles (score sums over j -> splittable) to keep VGPR demand ~110 < 128.
__global__ __launch_bounds__(256, 4)
void attn_kernel(const float* __restrict__ q_x,   // (B,T,64)
                 const float* __restrict__ kv_x,  // (B,T,127,64)
                 const float* __restrict__ Wk,    // (256,64)
                 const float* __restrict__ Wq,    // (256,64)
                 const float* __restrict__ Wv,    // (256,64)
                 const float* __restrict__ bias,  // (64,)
                 const float* __restrict__ Ws,    // (1,64)
                 const float* __restrict__ bs,    // (1,) -- cancels in softmax
                 float* __restrict__ out)         // (B,T,256)
{
    __shared__ __align__(16) float kv_f[NPAD * PITCH];   // 34816 B fp32, padded pitch
    __shared__ float qb_lds[CH];                         // 1 KB: query+bias per channel
    __shared__ float p_lds[NH][NPAD];                    // 2 KB: scores then probs
    __shared__ __align__(16) float wkv_lds[NH][KDIM];    // 1 KB

    const int bt   = blockIdx.x;
    const int tid  = threadIdx.x;
    const int h    = tid >> 6;    // wave index == head index
    const int lane = tid & 63;
    const int col  = lane & 15;   // MFMA n/m lane index
    const int quad = lane >> 4;   // MFMA k-group / row-group

    const float* __restrict__ kvg = kv_x + (size_t)bt * NKEY * KDIM;

    // ---- stage kv -> padded LDS (coalesced float4 in, bank-balanced out) ----
    #pragma unroll
    for (int i = 0; i < 8; ++i) {
        const int g  = i * 256 + tid;      // global float4 index, 0..2047
        const int n  = g >> 4;             // key row
        const int kk = g & 15;             // float4 within row
        float4 v = make_float4(0.f, 0.f, 0.f, 0.f);
        if (n < NKEY) v = ((const float4*)kvg)[g];
        *(float4*)&kv_f[n * PITCH + kk * 4] = v;   // row 127 zeroed
    }

    // ---- query_j + bias -> qb_lds[channel] ----
    {
        const float4* Wq4 = (const float4*)(Wq + (size_t)tid * KDIM);
        const float4* q4g = (const float4*)(q_x + (size_t)bt * KDIM);
        float4 qa = {0.f, 0.f, 0.f, 0.f};
        #pragma unroll
        for (int i = 0; i < 16; ++i) {
            float4 w = Wq4[i];
            float4 q4 = q4g[i];
            qa.x = fmaf(q4.x, w.x, qa.x);
            qa.y = fmaf(q4.y, w.y, qa.y);
            qa.z = fmaf(q4.z, w.z, qa.z);
            qa.w = fmaf(q4.w, w.w, qa.w);
        }
        qb_lds[tid] = (qa.x + qa.y) + (qa.z + qa.w) + bias[tid & 63];
    }

    __syncthreads();   // the ONLY barrier: kv_f + qb_lds ready

    // ---- scores: 2 passes over j-tiles (register diet), 8 n-tiles each ----
    float spartial[8] = {0.f, 0.f, 0.f, 0.f, 0.f, 0.f, 0.f, 0.f};

    #pragma unroll
    for (int pass = 0; pass < 2; ++pass) {
        // A-fragments for jt = 2*pass + jj (Wk rows from global, split hi/lo)
        short8 ahi[2][2], alo[2][2];
        float qbp[2][4], wsp[2][4];
        #pragma unroll
        for (int jj = 0; jj < 2; ++jj) {
            const int jt = 2 * pass + jj;
            #pragma unroll
            for (int ks = 0; ks < 2; ++ks) {
                const float* wrow = Wk + (size_t)(h * 64 + jt * 16 + col) * KDIM
                                       + ks * 32 + quad * 8;
                float4 a = *(const float4*)wrow;
                float4 b = *(const float4*)(wrow + 4);
                split8(a, b, ahi[jj][ks], alo[jj][ks]);
            }
            #pragma unroll
            for (int r = 0; r < 4; ++r) {
                const int j = jt * 16 + quad * 4 + r;
                qbp[jj][r] = qb_lds[h * 64 + j];
                wsp[jj][r] = Ws[j];
            }
        }

        for (int nt = 0; nt < 8; ++nt) {
            // B-fragments on the fly from padded fp32 LDS (bank-balanced b128)
            short8 bhi[2], blo[2];
            #pragma unroll
            for (int ks = 0; ks < 2; ++ks) {
                const float* p = &kv_f[(nt * 16 + col) * PITCH + ks * 32 + quad * 8];
                float4 a = *(const float4*)p;
                float4 b = *(const float4*)(p + 4);
                split8(a, b, bhi[ks], blo[ks]);
            }

            floatx4 acc[2];
            #pragma unroll
            for (int jj = 0; jj < 2; ++jj) {
                floatx4 c = {0.f, 0.f, 0.f, 0.f};
                c = __builtin_amdgcn_mfma_f32_16x16x32_bf16(ahi[jj][0], bhi[0], c, 0, 0, 0);
                c = __builtin_amdgcn_mfma_f32_16x16x32_bf16(ahi[jj][1], bhi[1], c, 0, 0, 0);
                c = __builtin_amdgcn_mfma_f32_16x16x32_bf16(ahi[jj][0], blo[0], c, 0, 0, 0);
                c = __builtin_amdgcn_mfma_f32_16x16x32_bf16(ahi[jj][1], blo[1], c, 0, 0, 0);
                c = __builtin_amdgcn_mfma_f32_16x16x32_bf16(alo[jj][0], bhi[0], c, 0, 0, 0);
                c = __builtin_amdgcn_mfma_f32_16x16x32_bf16(alo[jj][1], bhi[1], c, 0, 0, 0);
                acc[jj] = c;
            }

            // partial score: sum over this pass's 8 j-values
            // D layout: col = lane&15 = n in tile, row = quad*4 + r = j in jt
            float part = spartial[nt];
            #pragma unroll
            for (int jj = 0; jj < 2; ++jj)
                #pragma unroll
                for (int r = 0; r < 4; ++r)
                    part = fmaf(fast_tanh(acc[jj][r] + qbp[jj][r]), wsp[jj][r], part);
            spartial[nt] = part;
        }
    }

    // ---- reduce scores across quads, publish to p_lds ----
    #pragma unroll
    for (int nt = 0; nt < 8; ++nt) {
        float s = spartial[nt];
        s += __shfl_xor(s, 16, 64);
        s += __shfl_xor(s, 32, 64);
        if (lane < 16) p_lds[h][nt * 16 + lane] = s;
    }
    // no barrier: wave h is sole writer+reader of p_lds[h][*] (DS in-order)

    // ---- softmax over the 127 real keys (2 scores per lane) ----
    float invl;
    {
        float s_a = p_lds[h][lane];
        float s_b = p_lds[h][64 + lane];
        if (lane == 63) s_b = -1e30f;          // mask pad row 127
        float mx = fmaxf(s_a, s_b);
        #pragma unroll
        for (int off = 32; off > 0; off >>= 1)
            mx = fmaxf(mx, __shfl_xor(mx, off, 64));
        float pa = __expf(s_a - mx);
        float pb = __expf(s_b - mx);           // lane 63 -> 0
        float ls = pa + pb;
        #pragma unroll
        for (int off = 32; off > 0; off >>= 1)
            ls += __shfl_xor(ls, off, 64);
        invl = 1.f / ls;
        p_lds[h][lane]      = pa;              // unnormalized probs
        p_lds[h][64 + lane] = pb;              // p_lds[h][127] = 0 masks pad
    }

    // ---- Phase B (wave-private): wkv[h][:] = (sum_n p[n] * kv[n][:]) / l ----
    // lane (kk = col, nn = quad) accumulates k = 4kk..4kk+3 over rows n == nn (mod 4)
    {
        float4 a4 = make_float4(0.f, 0.f, 0.f, 0.f);
        #pragma unroll 4
        for (int i = 0; i < 32; ++i) {
            const int n = 4 * i + quad;
            float4 v = *(const float4*)&kv_f[n * PITCH + 4 * col];
            float pn = p_lds[h][n];            // 4 addrs/instr, distinct banks
            a4.x = fmaf(pn, v.x, a4.x);
            a4.y = fmaf(pn, v.y, a4.y);
            a4.z = fmaf(pn, v.z, a4.z);
            a4.w = fmaf(pn, v.w, a4.w);
        }
        #pragma unroll
        for (int off = 16; off <= 32; off <<= 1) {
            a4.x += __shfl_xor(a4.x, off, 64);
            a4.y += __shfl_xor(a4.y, off, 64);
            a4.z += __shfl_xor(a4.z, off, 64);
            a4.w += __shfl_xor(a4.w, off, 64);
        }
        if (lane < 16) {
            float4 r = make_float4(a4.x * invl, a4.y * invl, a4.z * invl, a4.w * invl);
            *(float4*)&wkv_lds[h][4 * col] = r;
        }
    }
    // no barrier: same-wave DS ordering (pattern proven in R3-R5)

    // ---- Phase C: out[j] = wkv[h,:] . Wv[j,:] ----
    {
        const float4* Wv4 = (const float4*)(Wv + (size_t)tid * KDIM);
        const float4* wv_row = (const float4*)wkv_lds[h];
        float4 oa = {0.f, 0.f, 0.f, 0.f};
        #pragma unroll
        for (int i = 0; i < 16; ++i) {
            float4 w = Wv4[i];
            float4 c = wv_row[i];                        // broadcast
            oa.x = fmaf(c.x, w.x, oa.x);
            oa.y = fmaf(c.y, w.y, oa.y);
            oa.z = fmaf(c.z, w.z, oa.z);
            oa.w = fmaf(c.w, w.w, oa.w);
        }
        out[(size_t)bt * CH + tid] = (oa.x + oa.y) + (oa.z + oa.w);
    }
}

extern "C" void kernel_launch(void* const* d_in, const int* in_sizes, int n_in,
                              void* d_out, int out_size, void* d_ws, size_t ws_size,
                              hipStream_t stream) {
    const float* q_x  = (const float*)d_in[0];
    const float* kv_x = (const float*)d_in[1];
    const float* Wk   = (const float*)d_in[2];
    const float* Wq   = (const float*)d_in[3];
    const float* Wv   = (const float*)d_in[4];
    const float* bias = (const float*)d_in[5];
    const float* Ws   = (const float*)d_in[6];
    const float* bs   = (const float*)d_in[7];
    float* out = (float*)d_out;

    attn_kernel<<<dim3(B * T), dim3(256), 0, stream>>>(
        q_x, kv_x, Wk, Wq, Wv, bias, Ws, bs, out);
}

// Round 7
// 121.459 us; speedup vs baseline: 1.2485x; 1.2441x over previous
//
#include <hip/hip_runtime.h>
#include <math.h>

#define B 8
#define T 128
#define NKEY 127   // t-1
#define NPAD 128   // padded key count (row 127 zeroed; prob forced to 0)
#define KDIM 64    // Q_DIM == KV_DIM
#define NH 4       // heads
#define CH 256     // NH*KDIM output channels
#define PITCH 68   // floats per kv row in LDS: 16B-aligned, bank-balanced

typedef short short8 __attribute__((ext_vector_type(8)));   // 8 bf16 (4 VGPRs)
typedef float floatx4 __attribute__((ext_vector_type(4)));  // MFMA C/D

// tanh(x) = 1 - 2/(e^{2x}+1). Saturates correctly at +/-inf, no clamp needed.
__device__ __forceinline__ float fast_tanh(float x) {
    float e = __expf(2.f * x);
    float r = __builtin_amdgcn_rcpf(e + 1.f);
    return fmaf(-2.f, r, 1.f);
}

// Truncation split: x = hi + lo, both bf16 (3-pass MFMA reconstructs ~fp32).
__device__ __forceinline__ void split8(const float4& a, const float4& b,
                                       short8& hi, short8& lo) {
    float x[8] = {a.x, a.y, a.z, a.w, b.x, b.y, b.z, b.w};
    #pragma unroll
    for (int i = 0; i < 8; ++i) {
        unsigned u = __float_as_uint(x[i]);
        hi[i] = (short)(u >> 16);                          // trunc to bf16
        float l = x[i] - __uint_as_float(u & 0xFFFF0000u); // exact residual
        lo[i] = (short)(__float_as_uint(l) >> 16);         // trunc residual
    }
}

// One workgroup per (b,t): 4 waves; wave h == head h.
// R7 = R6 structure with the two spill causes fixed:
//  (1) __launch_bounds__(256,2): arg2=4 made the backend cap VGPRs at 64 and
//      spill 150 MB of scratch (R4/R5/R6); arg2=2 (R3) gave 88 VGPRs, 0 spill.
//      Actual VGPR use (~110 <= 128) still yields 4 waves/SIMD in hardware.
//  (2) nt loops fully unrolled: spartial[nt] was dynamically indexed ->
//      whole array lived in scratch.
__global__ __launch_bounds__(256, 2)
void attn_kernel(const float* __restrict__ q_x,   // (B,T,64)
                 const float* __restrict__ kv_x,  // (B,T,127,64)
                 const float* __restrict__ Wk,    // (256,64)
                 const float* __restrict__ Wq,    // (256,64)
                 const float* __restrict__ Wv,    // (256,64)
                 const float* __restrict__ bias,  // (64,)
                 const float* __restrict__ Ws,    // (1,64)
                 const float* __restrict__ bs,    // (1,) -- cancels in softmax
                 float* __restrict__ out)         // (B,T,256)
{
    __shared__ __align__(16) float kv_f[NPAD * PITCH];   // 34816 B fp32, padded pitch
    __shared__ float qb_lds[CH];                         // 1 KB: query+bias per channel
    __shared__ float p_lds[NH][NPAD];                    // 2 KB: scores then probs
    __shared__ __align__(16) float wkv_lds[NH][KDIM];    // 1 KB

    const int bt   = blockIdx.x;
    const int tid  = threadIdx.x;
    const int h    = tid >> 6;    // wave index == head index
    const int lane = tid & 63;
    const int col  = lane & 15;   // MFMA n/m lane index
    const int quad = lane >> 4;   // MFMA k-group / row-group

    const float* __restrict__ kvg = kv_x + (size_t)bt * NKEY * KDIM;

    // ---- stage kv -> padded LDS (coalesced float4 in, bank-balanced out) ----
    #pragma unroll
    for (int i = 0; i < 8; ++i) {
        const int g  = i * 256 + tid;      // global float4 index, 0..2047
        const int n  = g >> 4;             // key row
        const int kk = g & 15;             // float4 within row
        float4 v = make_float4(0.f, 0.f, 0.f, 0.f);
        if (n < NKEY) v = ((const float4*)kvg)[g];
        *(float4*)&kv_f[n * PITCH + kk * 4] = v;   // row 127 zeroed
    }

    // ---- query_j + bias -> qb_lds[channel] ----
    {
        const float4* Wq4 = (const float4*)(Wq + (size_t)tid * KDIM);
        const float4* q4g = (const float4*)(q_x + (size_t)bt * KDIM);
        float4 qa = {0.f, 0.f, 0.f, 0.f};
        #pragma unroll
        for (int i = 0; i < 16; ++i) {
            float4 w = Wq4[i];
            float4 q4 = q4g[i];
            qa.x = fmaf(q4.x, w.x, qa.x);
            qa.y = fmaf(q4.y, w.y, qa.y);
            qa.z = fmaf(q4.z, w.z, qa.z);
            qa.w = fmaf(q4.w, w.w, qa.w);
        }
        qb_lds[tid] = (qa.x + qa.y) + (qa.z + qa.w) + bias[tid & 63];
    }

    __syncthreads();   // the ONLY barrier: kv_f + qb_lds ready

    // ---- scores: 2 passes over j-tiles (register diet), 8 n-tiles each ----
    float spartial[8] = {0.f, 0.f, 0.f, 0.f, 0.f, 0.f, 0.f, 0.f};

    #pragma unroll
    for (int pass = 0; pass < 2; ++pass) {
        // A-fragments for jt = 2*pass + jj (Wk rows from global, split hi/lo)
        short8 ahi[2][2], alo[2][2];
        float qbp[2][4], wsp[2][4];
        #pragma unroll
        for (int jj = 0; jj < 2; ++jj) {
            const int jt = 2 * pass + jj;
            #pragma unroll
            for (int ks = 0; ks < 2; ++ks) {
                const float* wrow = Wk + (size_t)(h * 64 + jt * 16 + col) * KDIM
                                       + ks * 32 + quad * 8;
                float4 a = *(const float4*)wrow;
                float4 b = *(const float4*)(wrow + 4);
                split8(a, b, ahi[jj][ks], alo[jj][ks]);
            }
            #pragma unroll
            for (int r = 0; r < 4; ++r) {
                const int j = jt * 16 + quad * 4 + r;
                qbp[jj][r] = qb_lds[h * 64 + j];
                wsp[jj][r] = Ws[j];
            }
        }

        #pragma unroll
        for (int nt = 0; nt < 8; ++nt) {
            // B-fragments on the fly from padded fp32 LDS (bank-balanced b128)
            short8 bhi[2], blo[2];
            #pragma unroll
            for (int ks = 0; ks < 2; ++ks) {
                const float* p = &kv_f[(nt * 16 + col) * PITCH + ks * 32 + quad * 8];
                float4 a = *(const float4*)p;
                float4 b = *(const float4*)(p + 4);
                split8(a, b, bhi[ks], blo[ks]);
            }

            floatx4 acc[2];
            #pragma unroll
            for (int jj = 0; jj < 2; ++jj) {
                floatx4 c = {0.f, 0.f, 0.f, 0.f};
                c = __builtin_amdgcn_mfma_f32_16x16x32_bf16(ahi[jj][0], bhi[0], c, 0, 0, 0);
                c = __builtin_amdgcn_mfma_f32_16x16x32_bf16(ahi[jj][1], bhi[1], c, 0, 0, 0);
                c = __builtin_amdgcn_mfma_f32_16x16x32_bf16(ahi[jj][0], blo[0], c, 0, 0, 0);
                c = __builtin_amdgcn_mfma_f32_16x16x32_bf16(ahi[jj][1], blo[1], c, 0, 0, 0);
                c = __builtin_amdgcn_mfma_f32_16x16x32_bf16(alo[jj][0], bhi[0], c, 0, 0, 0);
                c = __builtin_amdgcn_mfma_f32_16x16x32_bf16(alo[jj][1], bhi[1], c, 0, 0, 0);
                acc[jj] = c;
            }

            // partial score: sum over this pass's 8 j-values
            // D layout: col = lane&15 = n in tile, row = quad*4 + r = j in jt
            float part = spartial[nt];
            #pragma unroll
            for (int jj = 0; jj < 2; ++jj)
                #pragma unroll
                for (int r = 0; r < 4; ++r)
                    part = fmaf(fast_tanh(acc[jj][r] + qbp[jj][r]), wsp[jj][r], part);
            spartial[nt] = part;
        }
    }

    // ---- reduce scores across quads, publish to p_lds ----
    #pragma unroll
    for (int nt = 0; nt < 8; ++nt) {
        float s = spartial[nt];
        s += __shfl_xor(s, 16, 64);
        s += __shfl_xor(s, 32, 64);
        if (lane < 16) p_lds[h][nt * 16 + lane] = s;
    }
    // no barrier: wave h is sole writer+reader of p_lds[h][*] (DS in-order)

    // ---- softmax over the 127 real keys (2 scores per lane) ----
    float invl;
    {
        float s_a = p_lds[h][lane];
        float s_b = p_lds[h][64 + lane];
        if (lane == 63) s_b = -1e30f;          // mask pad row 127
        float mx = fmaxf(s_a, s_b);
        #pragma unroll
        for (int off = 32; off > 0; off >>= 1)
            mx = fmaxf(mx, __shfl_xor(mx, off, 64));
        float pa = __expf(s_a - mx);
        float pb = __expf(s_b - mx);           // lane 63 -> 0
        float ls = pa + pb;
        #pragma unroll
        for (int off = 32; off > 0; off >>= 1)
            ls += __shfl_xor(ls, off, 64);
        invl = 1.f / ls;
        p_lds[h][lane]      = pa;              // unnormalized probs
        p_lds[h][64 + lane] = pb;              // p_lds[h][127] = 0 masks pad
    }

    // ---- Phase B (wave-private): wkv[h][:] = (sum_n p[n] * kv[n][:]) / l ----
    // lane (kk = col, nn = quad) accumulates k = 4col..4col+3 over rows n == quad (mod 4)
    {
        float4 a4 = make_float4(0.f, 0.f, 0.f, 0.f);
        #pragma unroll 4
        for (int i = 0; i < 32; ++i) {
            const int n = 4 * i + quad;
            float4 v = *(const float4*)&kv_f[n * PITCH + 4 * col];
            float pn = p_lds[h][n];
            a4.x = fmaf(pn, v.x, a4.x);
            a4.y = fmaf(pn, v.y, a4.y);
            a4.z = fmaf(pn, v.z, a4.z);
            a4.w = fmaf(pn, v.w, a4.w);
        }
        #pragma unroll
        for (int off = 16; off <= 32; off <<= 1) {
            a4.x += __shfl_xor(a4.x, off, 64);
            a4.y += __shfl_xor(a4.y, off, 64);
            a4.z += __shfl_xor(a4.z, off, 64);
            a4.w += __shfl_xor(a4.w, off, 64);
        }
        if (lane < 16) {
            float4 r = make_float4(a4.x * invl, a4.y * invl, a4.z * invl, a4.w * invl);
            *(float4*)&wkv_lds[h][4 * col] = r;
        }
    }
    // no barrier: same-wave DS ordering (pattern proven in R3-R6)

    // ---- Phase C: out[j] = wkv[h,:] . Wv[j,:] ----
    {
        const float4* Wv4 = (const float4*)(Wv + (size_t)tid * KDIM);
        const float4* wv_row = (const float4*)wkv_lds[h];
        float4 oa = {0.f, 0.f, 0.f, 0.f};
        #pragma unroll
        for (int i = 0; i < 16; ++i) {
            float4 w = Wv4[i];
            float4 c = wv_row[i];                        // broadcast
            oa.x = fmaf(c.x, w.x, oa.x);
            oa.y = fmaf(c.y, w.y, oa.y);
            oa.z = fmaf(c.z, w.z, oa.z);
            oa.w = fmaf(c.w, w.w, oa.w);
        }
        out[(size_t)bt * CH + tid] = (oa.x + oa.y) + (oa.z + oa.w);
    }
}

extern "C" void kernel_launch(void* const* d_in, const int* in_sizes, int n_in,
                              void* d_out, int out_size, void* d_ws, size_t ws_size,
                              hipStream_t stream) {
    const float* q_x  = (const float*)d_in[0];
    const float* kv_x = (const float*)d_in[1];
    const float* Wk   = (const float*)d_in[2];
    const float* Wq   = (const float*)d_in[3];
    const float* Wv   = (const float*)d_in[4];
    const float* bias = (const float*)d_in[5];
    const float* Ws   = (const float*)d_in[6];
    const float* bs   = (const float*)d_in[7];
    float* out = (float*)d_out;

    attn_kernel<<<dim3(B * T), dim3(256), 0, stream>>>(
        q_x, kv_x, Wk, Wq, Wv, bias, Ws, bs, out);
}

// Round 8
// 116.517 us; speedup vs baseline: 1.3014x; 1.0424x over previous
//
#include <hip/hip_runtime.h>
#include <math.h>

#define B 8
#define T 128
#define NKEY 127   // t-1
#define NPAD 128   // padded key count (score row 127 forced to prob 0)
#define KDIM 64    // Q_DIM == KV_DIM
#define NH 4       // heads
#define CH 256     // NH*KDIM output channels

typedef short short8 __attribute__((ext_vector_type(8)));   // 8 bf16 (4 VGPRs)
typedef float floatx4 __attribute__((ext_vector_type(4)));  // MFMA C/D

// tanh(x) = 1 - 2/(e^{2x}+1). Saturates correctly at +/-inf, no clamp needed.
__device__ __forceinline__ float fast_tanh(float x) {
    float e = __expf(2.f * x);
    float r = __builtin_amdgcn_rcpf(e + 1.f);
    return fmaf(-2.f, r, 1.f);
}

// Truncation split: x = hi + lo, both bf16 (2-pass B-side reconstructs ~fp32).
__device__ __forceinline__ void split8(const float4& a, const float4& b,
                                       short8& hi, short8& lo) {
    float x[8] = {a.x, a.y, a.z, a.w, b.x, b.y, b.z, b.w};
    #pragma unroll
    for (int i = 0; i < 8; ++i) {
        unsigned u = __float_as_uint(x[i]);
        hi[i] = (short)(u >> 16);                          // trunc to bf16
        float l = x[i] - __uint_as_float(u & 0xFFFF0000u); // exact residual
        lo[i] = (short)(__float_as_uint(l) >> 16);         // trunc residual
    }
}

// Round-to-nearest-even bf16 (for A-side hi-only: halves error, no sign bias).
__device__ __forceinline__ void rne8(const float4& a, const float4& b, short8& hi) {
    float x[8] = {a.x, a.y, a.z, a.w, b.x, b.y, b.z, b.w};
    #pragma unroll
    for (int i = 0; i < 8; ++i) {
        unsigned u = __float_as_uint(x[i]);
        u += 0x7FFFu + ((u >> 16) & 1u);
        hi[i] = (short)(u >> 16);
    }
}

// One workgroup per (b,t): 4 waves; wave h == head h.
// R8 = R4 structure (the fastest round: pre-split bf16 hi/lo frag LDS, 0 bank
// conflicts, Phase-B global re-read) with its two defects fixed:
//  (1) __launch_bounds__(256,2) -- arg2=4 capped VGPRs at 64 and spilled
//      (R4: 11 MB, R5: 150 MB). R7 proved (256,2) -> 128 VGPR, no spill.
//  (2) A-side hi-only (RNE): A-frags 64->32 VGPRs, 24->16 MFMA/nt, single
//      j-pass. Score-path error += ~3e-4, well under the 3.5e-3 threshold.
__global__ __launch_bounds__(256, 2)
void attn_kernel(const float* __restrict__ q_x,   // (B,T,64)
                 const float* __restrict__ kv_x,  // (B,T,127,64)
                 const float* __restrict__ Wk,    // (256,64)
                 const float* __restrict__ Wq,    // (256,64)
                 const float* __restrict__ Wv,    // (256,64)
                 const float* __restrict__ bias,  // (64,)
                 const float* __restrict__ Ws,    // (1,64)
                 const float* __restrict__ bs,    // (1,) -- cancels in softmax
                 float* __restrict__ out)         // (B,T,256)
{
    __shared__ __align__(16) short bh_lds[16][64][8];    // 16 KB: B-frag hi [chunk][lane][8]
    __shared__ __align__(16) short bl_lds[16][64][8];    // 16 KB: B-frag lo
    __shared__ float qb_lds[CH];                         // 1 KB: query+bias per channel
    __shared__ float p_lds[NH][NPAD];                    // 2 KB: scores then probs
    __shared__ __align__(16) float wkv_lds[NH][KDIM];    // 1 KB -> total 36864 B

    const int bt   = blockIdx.x;
    const int tid  = threadIdx.x;
    const int h    = tid >> 6;    // wave index == head index
    const int lane = tid & 63;
    const int col  = lane & 15;   // MFMA n/m lane index
    const int quad = lane >> 4;   // MFMA k-group / row-group

    const float* __restrict__ kvg = kv_x + (size_t)bt * NKEY * KDIM;

    // ---- convert kv (global) -> fragment-ordered bf16 hi/lo LDS ----
    // chunk = nt*2+ks; write addr = chunk*1024 + lane*16: lane-linear, 0 conflicts.
    // Fragment content: kv[nt*16 + (lane&15)][ks*32 + (lane>>4)*8 + j]
    #pragma unroll
    for (int w = 0; w < 4; ++w) {
        const int chunk = w * 4 + h;          // each wave does 4 chunks
        const int nt = chunk >> 1, ks = chunk & 1;
        const int n  = nt * 16 + (lane & 15);
        const int k0 = ks * 32 + (lane >> 4) * 8;
        float4 a = make_float4(0.f, 0.f, 0.f, 0.f);
        float4 b = make_float4(0.f, 0.f, 0.f, 0.f);
        if (n < NKEY) {
            const float* p = kvg + (size_t)n * KDIM + k0;
            a = *(const float4*)p;
            b = *(const float4*)(p + 4);
        }
        short8 hi, lo;
        split8(a, b, hi, lo);
        *(short8*)&bh_lds[chunk][lane][0] = hi;
        *(short8*)&bl_lds[chunk][lane][0] = lo;
    }

    // ---- query_j + bias -> qb_lds[channel] ----
    {
        const float4* Wq4 = (const float4*)(Wq + (size_t)tid * KDIM);
        const float4* q4g = (const float4*)(q_x + (size_t)bt * KDIM);
        float4 qa = {0.f, 0.f, 0.f, 0.f};
        #pragma unroll
        for (int i = 0; i < 16; ++i) {
            float4 w = Wq4[i];
            float4 q4 = q4g[i];
            qa.x = fmaf(q4.x, w.x, qa.x);
            qa.y = fmaf(q4.y, w.y, qa.y);
            qa.z = fmaf(q4.z, w.z, qa.z);
            qa.w = fmaf(q4.w, w.w, qa.w);
        }
        qb_lds[tid] = (qa.x + qa.y) + (qa.z + qa.w) + bias[tid & 63];
    }

    // ---- A-fragments: Wk rows of this head, RNE bf16 hi only ----
    // A layout: lane holds Wk[h*64 + jt*16 + col][ks*32 + quad*8 + j]
    short8 ahi[4][2];
    #pragma unroll
    for (int jt = 0; jt < 4; ++jt)
        #pragma unroll
        for (int ks = 0; ks < 2; ++ks) {
            const float* wrow = Wk + (size_t)(h * 64 + jt * 16 + col) * KDIM
                                   + ks * 32 + quad * 8;
            float4 a = *(const float4*)wrow;
            float4 b = *(const float4*)(wrow + 4);
            rne8(a, b, ahi[jt][ks]);
        }

    __syncthreads();   // barrier: frags + qb ready

    // ---- per-lane qb / ws for epilogue: j = jt*16 + quad*4 + r ----
    float qbv[4][4], wsv[4][4];
    #pragma unroll
    for (int jt = 0; jt < 4; ++jt)
        #pragma unroll
        for (int r = 0; r < 4; ++r) {
            int j = jt * 16 + quad * 4 + r;
            qbv[jt][r] = qb_lds[h * 64 + j];
            wsv[jt][r] = Ws[j];
        }

    // ---- scores: 8 n-tiles of 16 keys; Ahi·(Bhi+Blo) 2-pass MFMA ----
    #pragma unroll
    for (int nt = 0; nt < 8; ++nt) {
        short8 bhi0 = *(const short8*)&bh_lds[nt * 2 + 0][lane][0];
        short8 blo0 = *(const short8*)&bl_lds[nt * 2 + 0][lane][0];
        short8 bhi1 = *(const short8*)&bh_lds[nt * 2 + 1][lane][0];
        short8 blo1 = *(const short8*)&bl_lds[nt * 2 + 1][lane][0];

        floatx4 acc[4];
        #pragma unroll
        for (int jt = 0; jt < 4; ++jt) {
            floatx4 c = {0.f, 0.f, 0.f, 0.f};
            c = __builtin_amdgcn_mfma_f32_16x16x32_bf16(ahi[jt][0], bhi0, c, 0, 0, 0);
            c = __builtin_amdgcn_mfma_f32_16x16x32_bf16(ahi[jt][1], bhi1, c, 0, 0, 0);
            c = __builtin_amdgcn_mfma_f32_16x16x32_bf16(ahi[jt][0], blo0, c, 0, 0, 0);
            c = __builtin_amdgcn_mfma_f32_16x16x32_bf16(ahi[jt][1], blo1, c, 0, 0, 0);
            acc[jt] = c;
        }

        // epilogue: score[n] = sum_j tanh(key + qb[j]) * ws[j]
        // D layout: col = lane&15 = n in tile, row = quad*4 + r = j in jt
        float partial = 0.f;
        #pragma unroll
        for (int jt = 0; jt < 4; ++jt)
            #pragma unroll
            for (int r = 0; r < 4; ++r)
                partial = fmaf(fast_tanh(acc[jt][r] + qbv[jt][r]), wsv[jt][r], partial);
        partial += __shfl_xor(partial, 16, 64);   // reduce across quads (same col)
        partial += __shfl_xor(partial, 32, 64);
        if (lane < 16) p_lds[h][nt * 16 + lane] = partial;
    }
    // no barrier: wave h is sole writer+reader of p_lds[h][*] (DS in-order)

    // ---- softmax over the 127 real keys (2 scores per lane) ----
    float invl;
    {
        float s_a = p_lds[h][lane];
        float s_b = p_lds[h][64 + lane];
        if (lane == 63) s_b = -1e30f;          // mask pad row 127
        float mx = fmaxf(s_a, s_b);
        #pragma unroll
        for (int off = 32; off > 0; off >>= 1)
            mx = fmaxf(mx, __shfl_xor(mx, off, 64));
        float pa = __expf(s_a - mx);
        float pb = __expf(s_b - mx);           // lane 63 -> 0
        float ls = pa + pb;
        #pragma unroll
        for (int off = 32; off > 0; off >>= 1)
            ls += __shfl_xor(ls, off, 64);
        invl = 1.f / ls;
        p_lds[h][lane]      = pa;              // unnormalized probs
        p_lds[h][64 + lane] = pb;              // p_lds[h][127] = 0 masks pad
    }

    // ---- Phase B: wkv[h][lane] = (sum_n p[n] * kv[n][lane]) / l ----
    // kv column reads from global: consecutive lanes -> consecutive addrs,
    // L2-hot (read during conversion ~us earlier). Probs broadcast from LDS.
    {
        const float* kvl = kvg + lane;
        float w0 = 0.f, w1 = 0.f, w2 = 0.f, w3 = 0.f;
        #pragma unroll 8
        for (int n4 = 0; n4 < NPAD; n4 += 4) {
            float4 p4 = *(const float4*)&p_lds[h][n4];       // uniform broadcast
            const int n3 = (n4 + 3 < NKEY) ? (n4 + 3) : 0;   // p4.w==0 there
            w0 = fmaf(p4.x, kvl[(size_t)(n4 + 0) * KDIM], w0);
            w1 = fmaf(p4.y, kvl[(size_t)(n4 + 1) * KDIM], w1);
            w2 = fmaf(p4.z, kvl[(size_t)(n4 + 2) * KDIM], w2);
            w3 = fmaf(p4.w, kvl[(size_t)n3 * KDIM], w3);
        }
        wkv_lds[h][lane] = ((w0 + w1) + (w2 + w3)) * invl;
    }
    // no barrier: wkv_lds[h] written and read only by wave h (DS in-order)

    // ---- Phase C: out[j] = wkv[h,:] . Wv[j,:] ----
    {
        const float4* Wv4 = (const float4*)(Wv + (size_t)tid * KDIM);
        const float4* wv_row = (const float4*)wkv_lds[h];
        float4 oa = {0.f, 0.f, 0.f, 0.f};
        #pragma unroll
        for (int i = 0; i < 16; ++i) {
            float4 w = Wv4[i];
            float4 c = wv_row[i];                        // broadcast
            oa.x = fmaf(c.x, w.x, oa.x);
            oa.y = fmaf(c.y, w.y, oa.y);
            oa.z = fmaf(c.z, w.z, oa.z);
            oa.w = fmaf(c.w, w.w, oa.w);
        }
        out[(size_t)bt * CH + tid] = (oa.x + oa.y) + (oa.z + oa.w);
    }
}

extern "C" void kernel_launch(void* const* d_in, const int* in_sizes, int n_in,
                              void* d_out, int out_size, void* d_ws, size_t ws_size,
                              hipStream_t stream) {
    const float* q_x  = (const float*)d_in[0];
    const float* kv_x = (const float*)d_in[1];
    const float* Wk   = (const float*)d_in[2];
    const float* Wq   = (const float*)d_in[3];
    const float* Wv   = (const float*)d_in[4];
    const float* bias = (const float*)d_in[5];
    const float* Ws   = (const float*)d_in[6];
    const float* bs   = (const float*)d_in[7];
    float* out = (float*)d_out;

    attn_kernel<<<dim3(B * T), dim3(256), 0, stream>>>(
        q_x, kv_x, Wk, Wq, Wv, bias, Ws, bs, out);
}